// Round 6
// baseline (289.173 us; speedup 1.0000x reference)
//
#include <hip/hip_runtime.h>

#define TOK 2048
#define DDIM 1024
#define HDIM 1408
#define ENUM 8
#define NSLOT (2 * TOK)
#define UP_NB 22   // HDIM / 64
#define UP_KS 32   // DDIM / 32
#define DN_NB 16   // DDIM / 64
#define DN_KS 44   // HDIM / 32
#define DN_KH 22   // DN_KS / 2 (K-split halves)
#define W1C_BLK 5632     // 16 z(e,tensor) * 32 ks * 11 cgrp(128 cols)
#define GATE_BLK 512     // 2048 tokens / 4 per block

typedef unsigned int uint;
typedef unsigned short ushort;
typedef unsigned long long ull;

using bf16x8 = __attribute__((ext_vector_type(8))) __bf16;
using f32x4  = __attribute__((ext_vector_type(4))) float;

__device__ __forceinline__ float silu_f(float g) {
    return g / (1.0f + __expf(-g));
}

__device__ __forceinline__ ushort cvt_bf16(float f) {
    uint u = __float_as_uint(f);
    u += 0x7FFFu + ((u >> 16) & 1u);   // RNE
    return (ushort)(u >> 16);
}

// async global->LDS: per-lane global address, LDS dest = wave-uniform base + lane*16
__device__ __forceinline__ void gl2lds16(const void* g, void* l) {
    __builtin_amdgcn_global_load_lds(
        (const __attribute__((address_space(1))) uint*)g,
        (__attribute__((address_space(3))) uint*)l, 16, 0, 0);
}

// ---- cast body: fp32 [32 rows][CW cols] slab -> bf16 tiles [nn(64)][kk(32)]
//      CW=128: 512B/row contiguous reads; CW=256: 1KB/row. LDS-staged
//      transpose, pad +4 (stride mod 32 = 4, consecutive-lane reads -> 
//      consecutive banks). Stores 32-64B contiguous per thread. ------------
template <int CW>
__device__ __forceinline__ void cast_body(
    const float* __restrict__ src, ushort* __restrict__ dst,
    int N, int KS, int NB, int e, int ks, int cgrp, int tid, float* Ls)
{
    const int LSTR = CW + 4;
    const float* st = src + (size_t)e * ((size_t)KS * 32) * N + (size_t)(ks * 32) * N + cgrp * CW;
    const int r = tid >> 3;
    const int fc = (tid & 7) * 4;
    const float* srow = st + (size_t)r * N + fc;
    float* lrow = Ls + r * LSTR + fc;
#pragma unroll
    for (int p = 0; p < CW / 32; ++p) {
        float4 v = *(const float4*)(srow + p * 32);
        lrow[p * 32 + 0] = v.x; lrow[p * 32 + 1] = v.y;
        lrow[p * 32 + 2] = v.z; lrow[p * 32 + 3] = v.w;
    }
    __syncthreads();
    const int nn = tid & 63;
    const int t2g = tid >> 6;
    if (CW == 256) {
        const int t2 = t2g;                 // 4 tiles of 64 cols
        const int nb = cgrp * 4 + t2;
        ushort* dt = dst + ((((size_t)e * NB + nb) * KS) + ks) * 2048 + nn * 32;
        const float* lc = Ls + t2 * 64 + nn;
        ushort o[32];
#pragma unroll
        for (int j = 0; j < 32; ++j) o[j] = cvt_bf16(lc[j * LSTR]);
#pragma unroll
        for (int q = 0; q < 4; ++q) *(uint4*)(dt + q * 8) = *(uint4*)(o + q * 8);
    } else {
        const int t2 = t2g >> 1;            // 2 tiles of 64 cols
        const int kg = t2g & 1;             // kk half
        const int nb = cgrp * 2 + t2;
        ushort* dt = dst + ((((size_t)e * NB + nb) * KS) + ks) * 2048 + nn * 32 + kg * 16;
        const float* lc = Ls + (kg * 16) * LSTR + t2 * 64 + nn;
        ushort o[16];
#pragma unroll
        for (int j = 0; j < 16; ++j) o[j] = cvt_bf16(lc[j * LSTR]);
#pragma unroll
        for (int q = 0; q < 2; ++q) *(uint4*)(dt + q * 8) = *(uint4*)(o + q * 8);
    }
}

// ---- kernel 1: w1g/w1u cast (512B-contiguous rows) + gate1 ---------------
__global__ __launch_bounds__(256) void w1cast_gate_kernel(
    const float* __restrict__ w1g, const float* __restrict__ w1u,
    ushort* __restrict__ BgP, ushort* __restrict__ BuP,
    const float* __restrict__ x, const float* __restrict__ gw,
    int* __restrict__ tinfo, float* __restrict__ wslot, ushort* __restrict__ xb)
{
    __shared__ float Ls[32][132];
    const int bid = blockIdx.x;
    const int tid = threadIdx.x;

    if (bid < W1C_BLK) {
        const int z16 = bid / 352;          // 352 = 32 ks * 11 cgrp
        const int rem = bid - z16 * 352;
        const int ks = rem / 11;
        const int cgrp = rem - ks * 11;
        cast_body<128>((z16 & 8) ? w1u : w1g, (z16 & 8) ? BuP : BgP,
                       HDIM, UP_KS, UP_NB, z16 & 7, ks, cgrp, tid, &Ls[0][0]);
        return;
    }

    // ---- gate1: 4 tokens per block, one wave each ----
    const int t = (bid - W1C_BLK) * 4 + (tid >> 6);
    const int lane = tid & 63;
    const float* xr = x + (size_t)t * DDIM;
    ushort* xbr = xb + (size_t)t * DDIM;
    float xv[16];
#pragma unroll
    for (int i = 0; i < 16; ++i) xv[i] = xr[lane + 64 * i];
#pragma unroll
    for (int i = 0; i < 16; ++i) xbr[lane + 64 * i] = cvt_bf16(xv[i]);
    float logit[ENUM];
#pragma unroll
    for (int e = 0; e < ENUM; ++e) {
        const float* gr = gw + (size_t)e * DDIM;
        float acc = 0.f;
#pragma unroll
        for (int i = 0; i < 16; ++i) acc += xv[i] * gr[lane + 64 * i];
#pragma unroll
        for (int s = 32; s > 0; s >>= 1) acc += __shfl_xor(acc, s, 64);
        logit[e] = acc;
    }
    if (lane == 0) {
        float mx = logit[0];
#pragma unroll
        for (int e = 1; e < ENUM; ++e) mx = fmaxf(mx, logit[e]);
        float p[ENUM]; float se = 0.f;
#pragma unroll
        for (int e = 0; e < ENUM; ++e) { p[e] = __expf(logit[e] - mx); se += p[e]; }
        float inv = 1.0f / se;
#pragma unroll
        for (int e = 0; e < ENUM; ++e) p[e] *= inv;
        int i0 = 0;
#pragma unroll
        for (int e = 1; e < ENUM; ++e) if (p[e] > p[i0]) i0 = e;
        int i1 = (i0 == 0) ? 1 : 0;
#pragma unroll
        for (int e = 0; e < ENUM; ++e) if (e != i0 && p[e] > p[i1]) i1 = e;
        tinfo[t] = i0 | (i1 << 4);
        wslot[(t << 1)] = p[i0];
        wslot[(t << 1) | 1] = p[i1];
    }
}

// ---- gate2: 8 blocks, wave-aggregated ballot compaction ------------------
__global__ __launch_bounds__(256) void gate2_kernel(
    const int* __restrict__ tinfo, int* __restrict__ counts, int* __restrict__ toks)
{
    const int e = blockIdx.x;
    const int tid = threadIdx.x;
    const int lane = tid & 63;
    __shared__ int cnt;
    if (tid == 0) cnt = 0;
    __syncthreads();
    int* te = toks + e * TOK;
    for (int t = tid; t < TOK; t += 256) {
        int info = tinfo[t];
        ull m0 = __ballot((info & 15) == e);
        if (m0) {
            int base;
            if (lane == 0) base = atomicAdd(&cnt, __popcll(m0));
            base = __shfl(base, 0, 64);
            if ((m0 >> lane) & 1)
                te[base + __popcll(m0 & ((1ull << lane) - 1))] = (t << 1);
        }
        ull m1 = __ballot((info >> 4) == e);
        if (m1) {
            int base;
            if (lane == 0) base = atomicAdd(&cnt, __popcll(m1));
            base = __shfl(base, 0, 64);
            if ((m1 >> lane) & 1)
                te[base + __popcll(m1 & ((1ull << lane) - 1))] = (t << 1) | 1;
        }
    }
    __syncthreads();
    if (tid == 0) counts[e] = cnt;
}

// ---- up + w2cast fused: z<4 -> w2 cast (1KB-contiguous rows), overlapping
//      with GEMM blocks; z>=4 -> up GEMM e=z-4. LDS union (both 33280 B). --
__global__ __launch_bounds__(256, 4) void up_mfma(
    const ushort* __restrict__ xb, const ushort* __restrict__ BgP,
    const ushort* __restrict__ BuP, const int* __restrict__ counts,
    const int* __restrict__ toks, ushort* __restrict__ Hbuf,
    const float* __restrict__ w2, ushort* __restrict__ W2P)
{
    __shared__ union {
        struct {
            ushort As[2][128][32];
            ushort Bgs[2][64][32];
            ushort Bus[2][64][32];
            int rowslot[128];
        } g;
        float Ls[32][260];
    } sm;

    const int z = blockIdx.z;
    const int tid = threadIdx.x;

    if (z < 4) {
        // w2 cast: 1408 blocks = 8 e * 44 ks * 4 cgrp(256 cols)
        const int cb = z * 352 + blockIdx.y * 22 + blockIdx.x;
        const int e = cb / 176;             // 176 = 44 ks * 4 cgrp
        const int rem = cb - e * 176;
        const int ks = rem >> 2;
        const int cgrp = rem & 3;
        cast_body<256>(w2, W2P, DDIM, DN_KS, DN_NB, e, ks, cgrp, tid, &sm.Ls[0][0]);
        return;
    }

    const int e = z - 4;
    const int cnt = counts[e];
    const int m0 = blockIdx.y * 128;
    if (m0 >= cnt) return;
    const int nb = blockIdx.x;
    const int w = tid >> 6;
    const int lane = tid & 63;
    const int q = lane >> 4;
    const int l15 = lane & 15;
    const int wr = w >> 1;   // 0..1 : m half (64 rows)
    const int wc = w & 1;    // 0..1 : n half (32 cols)

    if (tid < 128) sm.g.rowslot[tid] = (m0 + tid < cnt) ? toks[e * TOK + m0 + tid] : -1;
    __syncthreads();

    const int srow = w * 16 + (lane >> 2);
    const int clog = (((lane & 3) + 4 - ((srow >> 1) & 3)) & 3) * 8;
    const int as0 = sm.g.rowslot[srow];
    const int as1 = sm.g.rowslot[srow + 64];
    const ushort* agp0 = xb + (size_t)(as0 < 0 ? 0 : (as0 >> 1)) * DDIM + clog;
    const ushort* agp1 = xb + (size_t)(as1 < 0 ? 0 : (as1 >> 1)) * DDIM + clog;
    const size_t tb = (size_t)(e * UP_NB + nb) * UP_KS * 2048;
    const ushort* bgp = BgP + tb + srow * 32 + clog;
    const ushort* bup = BuP + tb + srow * 32 + clog;

    const int coff = ((q + (l15 >> 1)) & 3) * 8;

    f32x4 accg[4][2], accu[4][2];
#pragma unroll
    for (int i = 0; i < 4; ++i)
#pragma unroll
        for (int j = 0; j < 2; ++j) { accg[i][j] = (f32x4)0.f; accu[i][j] = (f32x4)0.f; }

#define UP_PREFETCH(KSV, B)                                             \
    {                                                                   \
        gl2lds16(agp0 + (KSV) * 32, &sm.g.As[B][w * 16][0]);            \
        gl2lds16(agp1 + (KSV) * 32, &sm.g.As[B][64 + w * 16][0]);       \
        gl2lds16(bgp + (size_t)(KSV) * 2048, &sm.g.Bgs[B][w * 16][0]);  \
        gl2lds16(bup + (size_t)(KSV) * 2048, &sm.g.Bus[B][w * 16][0]);  \
    }

    UP_PREFETCH(0, 0);
    __syncthreads();

    for (int ks = 0; ks < UP_KS; ++ks) {
        const int cur = ks & 1;
        const int nxt = cur ^ 1;
        if (ks + 1 < UP_KS) UP_PREFETCH(ks + 1, nxt);

        bf16x8 a[4], bg[2], bu[2];
#pragma unroll
        for (int mi = 0; mi < 4; ++mi)
            a[mi] = *(const bf16x8*)&sm.g.As[cur][wr * 64 + mi * 16 + l15][coff];
#pragma unroll
        for (int ni = 0; ni < 2; ++ni) {
            bg[ni] = *(const bf16x8*)&sm.g.Bgs[cur][wc * 32 + ni * 16 + l15][coff];
            bu[ni] = *(const bf16x8*)&sm.g.Bus[cur][wc * 32 + ni * 16 + l15][coff];
        }
#pragma unroll
        for (int mi = 0; mi < 4; ++mi)
#pragma unroll
            for (int ni = 0; ni < 2; ++ni) {
                accg[mi][ni] = __builtin_amdgcn_mfma_f32_16x16x32_bf16(a[mi], bg[ni], accg[mi][ni], 0, 0, 0);
                accu[mi][ni] = __builtin_amdgcn_mfma_f32_16x16x32_bf16(a[mi], bu[ni], accu[mi][ni], 0, 0, 0);
            }
        __syncthreads();   // drains prefetch vmem + protects buffer swap
    }
#undef UP_PREFETCH

#pragma unroll
    for (int mi = 0; mi < 4; ++mi) {
#pragma unroll
        for (int r = 0; r < 4; ++r) {
            int ml = wr * 64 + mi * 16 + q * 4 + r;
            int slot = sm.g.rowslot[ml];
            if (slot < 0) continue;
            ushort* hrow = Hbuf + (size_t)slot * HDIM + nb * 64 + wc * 32 + l15;
#pragma unroll
            for (int ni = 0; ni < 2; ++ni)
                hrow[ni * 16] = cvt_bf16(silu_f(accg[mi][ni][r]) * accu[mi][ni][r]);
        }
    }
}

// ---- down: Ybuf partials = Hbuf[slot] @ w2[e]; TM=128 TN=128, K-split 2,
//      dbuf, swizzled; 4 waves in 2x2, wave tile 64m x 64n ------------------
__global__ __launch_bounds__(256, 4) void down_mfma(
    const ushort* __restrict__ Hbuf, const ushort* __restrict__ W2P,
    const int* __restrict__ counts, const int* __restrict__ toks,
    float* __restrict__ Ybuf)
{
    const int z = blockIdx.z;           // 0..15: expert*2 + K-half
    const int e = z >> 1;
    const int kh = z & 1;
    const int cnt = counts[e];
    const int m0 = blockIdx.y * 128;
    if (m0 >= cnt) return;
    const int nb = blockIdx.x;          // 0..7, 128-wide N blocks
    const int tid = threadIdx.x;
    const int w = tid >> 6;
    const int lane = tid & 63;
    const int q = lane >> 4;
    const int l15 = lane & 15;
    const int wr = w >> 1;
    const int wc = w & 1;

    __shared__ ushort As[2][128][32];
    __shared__ ushort Bs[2][128][32];
    __shared__ int rowslot[128];

    if (tid < 128) rowslot[tid] = (m0 + tid < cnt) ? toks[e * TOK + m0 + tid] : -1;
    __syncthreads();

    const int srow = w * 16 + (lane >> 2);
    const int clog = (((lane & 3) + 4 - ((srow >> 1) & 3)) & 3) * 8;
    const int as0 = rowslot[srow];
    const int as1 = rowslot[srow + 64];
    const ushort* agp0 = Hbuf + (size_t)(as0 < 0 ? 0 : as0) * HDIM + kh * (DN_KH * 32) + clog;
    const ushort* agp1 = Hbuf + (size_t)(as1 < 0 ? 0 : as1) * HDIM + kh * (DN_KH * 32) + clog;
    const int nb2 = nb * 2;
    const ushort* bp0 = W2P + ((size_t)(e * DN_NB + nb2) * DN_KS + kh * DN_KH) * 2048 + srow * 32 + clog;
    const ushort* bp1 = W2P + ((size_t)(e * DN_NB + nb2 + 1) * DN_KS + kh * DN_KH) * 2048 + srow * 32 + clog;

    const int coff = ((q + (l15 >> 1)) & 3) * 8;

    f32x4 acc[4][4];
#pragma unroll
    for (int i = 0; i < 4; ++i)
#pragma unroll
        for (int j = 0; j < 4; ++j) acc[i][j] = (f32x4)0.f;

#define DN_PREFETCH(KSV, B)                                           \
    {                                                                 \
        gl2lds16(agp0 + (KSV) * 32, &As[B][w * 16][0]);               \
        gl2lds16(agp1 + (KSV) * 32, &As[B][64 + w * 16][0]);          \
        gl2lds16(bp0 + (size_t)(KSV) * 2048, &Bs[B][w * 16][0]);      \
        gl2lds16(bp1 + (size_t)(KSV) * 2048, &Bs[B][64 + w * 16][0]); \
    }

    DN_PREFETCH(0, 0);
    __syncthreads();

    for (int ks = 0; ks < DN_KH; ++ks) {
        const int cur = ks & 1;
        const int nxt = cur ^ 1;
        if (ks + 1 < DN_KH) DN_PREFETCH(ks + 1, nxt);

        bf16x8 a[4], b[4];
#pragma unroll
        for (int mi = 0; mi < 4; ++mi)
            a[mi] = *(const bf16x8*)&As[cur][wr * 64 + mi * 16 + l15][coff];
#pragma unroll
        for (int ni = 0; ni < 4; ++ni)
            b[ni] = *(const bf16x8*)&Bs[cur][wc * 64 + ni * 16 + l15][coff];
#pragma unroll
        for (int mi = 0; mi < 4; ++mi)
#pragma unroll
            for (int ni = 0; ni < 4; ++ni)
                acc[mi][ni] = __builtin_amdgcn_mfma_f32_16x16x32_bf16(a[mi], b[ni], acc[mi][ni], 0, 0, 0);
        __syncthreads();
    }
#undef DN_PREFETCH

    float* Yp = Ybuf + (size_t)kh * NSLOT * DDIM;
#pragma unroll
    for (int mi = 0; mi < 4; ++mi) {
#pragma unroll
        for (int r = 0; r < 4; ++r) {
            int ml = wr * 64 + mi * 16 + q * 4 + r;
            int slot = rowslot[ml];
            if (slot < 0) continue;
            float* yr = Yp + (size_t)slot * DDIM + nb * 128 + wc * 64 + l15;
#pragma unroll
            for (int ni = 0; ni < 4; ++ni)
                yr[ni * 16] = acc[mi][ni][r];
        }
    }
}

// ---- combine: y[t] = w0*(Y0[2t]+Y1[2t]) + w1*(Y0[2t+1]+Y1[2t+1]) ---------
__global__ __launch_bounds__(256) void combine_kernel(
    const float* __restrict__ Ybuf, const float* __restrict__ wslot,
    float* __restrict__ y)
{
    const int t = blockIdx.x;
    const int j = threadIdx.x * 4;
    const float w0 = wslot[2 * t];
    const float w1 = wslot[2 * t + 1];
    const float* y00 = Ybuf + ((size_t)2 * t) * DDIM + j;
    const float* y01 = Ybuf + ((size_t)2 * t + 1) * DDIM + j;
    const float* y10 = y00 + (size_t)NSLOT * DDIM;
    const float* y11 = y01 + (size_t)NSLOT * DDIM;
    float4 a0 = *(const float4*)y00;
    float4 b0 = *(const float4*)y01;
    float4 a1 = *(const float4*)y10;
    float4 b1 = *(const float4*)y11;
    float4 o;
    o.x = w0 * (a0.x + a1.x) + w1 * (b0.x + b1.x);
    o.y = w0 * (a0.y + a1.y) + w1 * (b0.y + b1.y);
    o.z = w0 * (a0.z + a1.z) + w1 * (b0.z + b1.z);
    o.w = w0 * (a0.w + a1.w) + w1 * (b0.w + b1.w);
    *(float4*)(y + (size_t)t * DDIM + j) = o;
}

extern "C" void kernel_launch(void* const* d_in, const int* in_sizes, int n_in,
                              void* d_out, int out_size, void* d_ws, size_t ws_size,
                              hipStream_t stream) {
    const float* x   = (const float*)d_in[0];
    const float* gw  = (const float*)d_in[1];
    const float* w1g = (const float*)d_in[2];
    const float* w1u = (const float*)d_in[3];
    const float* w2  = (const float*)d_in[4];
    float* y = (float*)d_out;
    char* ws = (char*)d_ws;

    // workspace layout (Ybuf [2 K-halves] aliases BgP/BuP region — dead after up_mfma)
    size_t off = 0;
    int*    counts = (int*)(ws + off);   off += 256;
    int*    toks   = (int*)(ws + off);   off += (size_t)ENUM * TOK * 4;   // 64 KB
    float*  wslot  = (float*)(ws + off); off += (size_t)NSLOT * 4;        // 16 KB
    int*    tinfo  = (int*)(ws + off);   off += (size_t)TOK * 4;          // 8 KB
    off = (off + 255) & ~(size_t)255;
    ushort* xb     = (ushort*)(ws + off); off += (size_t)TOK * DDIM * 2;  // 4 MB
    size_t regA = off;                                                    // 46 MB region
    ushort* BgP  = (ushort*)(ws + regA);
    ushort* BuP  = (ushort*)(ws + regA + (size_t)ENUM * DDIM * HDIM * 2);
    float*  Ybuf = (float*)(ws + regA);                                   // 33.6 MB alias
    off = regA + (size_t)2 * ENUM * DDIM * HDIM * 2;
    ushort* W2P  = (ushort*)(ws + off);  off += (size_t)ENUM * HDIM * DDIM * 2; // 23 MB
    ushort* Hbuf = (ushort*)(ws + off);                                         // 11.5 MB

    w1cast_gate_kernel<<<W1C_BLK + GATE_BLK, 256, 0, stream>>>(
        w1g, w1u, BgP, BuP, x, gw, tinfo, wslot, xb);
    gate2_kernel<<<ENUM, 256, 0, stream>>>(tinfo, counts, toks);

    up_mfma<<<dim3(UP_NB, TOK / 128, 12), 256, 0, stream>>>(
        xb, BgP, BuP, counts, toks, Hbuf, w2, W2P);
    down_mfma<<<dim3(DDIM / 128, TOK / 128, 16), 256, 0, stream>>>(Hbuf, W2P, counts, toks, Ybuf);
    combine_kernel<<<TOK, 256, 0, stream>>>(Ybuf, wslot, y);
}